// Round 1
// baseline (210.933 us; speedup 1.0000x reference)
//
#include <hip/hip_runtime.h>

// Problem constants: B=8, C=512, H=W=32, HW=1024, M=B*HW=8192
// scale = 1/sqrt(512); logit = mean over 8 images of per-image max, * scale

typedef __attribute__((ext_vector_type(8))) short bf16x8;
typedef __attribute__((ext_vector_type(4))) float f32x4;

__device__ __forceinline__ unsigned short f2bf(float f) {
  unsigned u = __builtin_bit_cast(unsigned, f);
  u += 0x7FFFu + ((u >> 16) & 1u);   // round-to-nearest-even
  return (unsigned short)(u >> 16);
}

__device__ __forceinline__ void gload_lds16(const void* g, void* l) {
  __builtin_amdgcn_global_load_lds(
      (const __attribute__((address_space(1))) unsigned int*)g,
      (__attribute__((address_space(3))) unsigned int*)l, 16, 0, 0);
}

// ---------------------------------------------------------------------------
// K0a: x [b][c][p] fp32  ->  xt [b*1024+p][c] bf16   (LDS-tiled transpose)
// grid (16 p-tiles, 8 c-tiles, 8 b), block 256
__global__ __launch_bounds__(256) void transpose_x(const float* __restrict__ x,
                                                   short* __restrict__ xt) {
  const int p0 = blockIdx.x * 64, c0 = blockIdx.y * 64, b = blockIdx.z;
  __shared__ float t[64][65];   // t[p][c]
  const int u = threadIdx.x;
  {
    const int p4 = u & 15, cr = u >> 4;
    for (int cc = 0; cc < 4; ++cc) {
      const int c = cc * 16 + cr;
      const float4 v = *(const float4*)&x[((size_t)(b * 512 + c0 + c)) * 1024 + p0 + p4 * 4];
      t[p4 * 4 + 0][c] = v.x;
      t[p4 * 4 + 1][c] = v.y;
      t[p4 * 4 + 2][c] = v.z;
      t[p4 * 4 + 3][c] = v.w;
    }
  }
  __syncthreads();
  {
    const int c4 = u & 15, pr = u >> 4;
    for (int pp = 0; pp < 4; ++pp) {
      const int p = pp * 16 + pr;
      ushort4 o;
      o.x = f2bf(t[p][c4 * 4 + 0]);
      o.y = f2bf(t[p][c4 * 4 + 1]);
      o.z = f2bf(t[p][c4 * 4 + 2]);
      o.w = f2bf(t[p][c4 * 4 + 3]);
      *(ushort4*)&xt[((size_t)(b * 1024 + p0 + p)) * 512 + c0 + c4 * 4] = o;
    }
  }
}

// ---------------------------------------------------------------------------
// K0b: Wq|Wk|W6 fp32 [512][512] each -> wcat bf16 [1536][512]
__global__ __launch_bounds__(256) void pack_w(const float* __restrict__ Wq,
                                              const float* __restrict__ Wk,
                                              const float* __restrict__ W6,
                                              short* __restrict__ wcat) {
  const int i = blockIdx.x * 256 + threadIdx.x;  // 196608 threads, 4 elems each
  const int idx = i * 4;
  const float* src = (idx < 262144) ? Wq : (idx < 524288) ? Wk : W6;
  const float4 v = *(const float4*)&src[idx & 262143];
  ushort4 o;
  o.x = f2bf(v.x); o.y = f2bf(v.y); o.z = f2bf(v.z); o.w = f2bf(v.w);
  *(ushort4*)&wcat[idx] = o;
}

// ---------------------------------------------------------------------------
// K1: C[8192][1536] = xt @ wcat^T ; cols 0..1023 -> qk bf16 (+bias), 1024..1535 -> z fp32
// m97 structure: 128x128 tile, BK=32, 256 threads (4 waves, 2x2 of 64x64)
__global__ __launch_bounds__(256) void gemm_qkz(const short* __restrict__ xt,
                                                const short* __restrict__ wcat,
                                                const float* __restrict__ bq,
                                                const float* __restrict__ bk,
                                                short* __restrict__ qk,
                                                float* __restrict__ z) {
  __shared__ short lds_a[128 * 32];
  __shared__ short lds_b[128 * 32];
  const int tid = threadIdx.x;
  const int w = tid >> 6, lane = tid & 63;
  const int wr = w >> 1, wc = w & 1;
  const int quad = lane >> 4, lcol = lane & 15;
  const int srow = w * 16 + (lane >> 2);  // staging row within 64-row chunk
  const int skoff = (lane & 3) * 8;       // staging k offset (bf16 elems)
  const int m0 = blockIdx.x * 128;
  const int n0 = blockIdx.y * 128;

  f32x4 acc[4][4];
#pragma unroll
  for (int i = 0; i < 4; ++i)
#pragma unroll
    for (int j = 0; j < 4; ++j)
#pragma unroll
      for (int r = 0; r < 4; ++r) acc[i][j][r] = 0.f;

  const short* Abase = xt + (size_t)(m0 + srow) * 512 + skoff;
  const short* Bbase = wcat + (size_t)(n0 + srow) * 512 + skoff;
  short* la = lds_a + (w * 16) * 32;  // wave-uniform LDS dest
  short* lb = lds_b + (w * 16) * 32;

  for (int kt = 0; kt < 16; ++kt) {
    const int kb = kt * 32;
    __syncthreads();
    gload_lds16(Abase + kb, la);
    gload_lds16(Abase + kb + (size_t)64 * 512, la + 64 * 32);
    gload_lds16(Bbase + kb, lb);
    gload_lds16(Bbase + kb + (size_t)64 * 512, lb + 64 * 32);
    __syncthreads();
    bf16x8 af[4], bf[4];
#pragma unroll
    for (int i = 0; i < 4; ++i)
      af[i] = *(const bf16x8*)&lds_a[(wr * 64 + i * 16 + lcol) * 32 + quad * 8];
#pragma unroll
    for (int j = 0; j < 4; ++j)
      bf[j] = *(const bf16x8*)&lds_b[(wc * 64 + j * 16 + lcol) * 32 + quad * 8];
#pragma unroll
    for (int i = 0; i < 4; ++i)
#pragma unroll
      for (int j = 0; j < 4; ++j)
        acc[i][j] = __builtin_amdgcn_mfma_f32_16x16x32_bf16(af[i], bf[j], acc[i][j], 0, 0, 0);
  }

  const int region = (int)blockIdx.y >> 2;  // 0=q, 1=k, 2=z (uniform per block)
  if (region < 2) {
    const float* bias = region ? bk : bq;
#pragma unroll
    for (int i = 0; i < 4; ++i)
#pragma unroll
      for (int j = 0; j < 4; ++j) {
        const int row = m0 + wr * 64 + i * 16 + quad * 4;
        const int col = n0 + wc * 64 + j * 16 + lcol;  // 0..1023
        const float bv = bias[col & 511];
#pragma unroll
        for (int r = 0; r < 4; ++r)
          qk[(size_t)(row + r) * 1024 + col] = (short)f2bf(acc[i][j][r] + bv);
      }
  } else {
#pragma unroll
    for (int i = 0; i < 4; ++i)
#pragma unroll
      for (int j = 0; j < 4; ++j) {
        const int row = m0 + wr * 64 + i * 16 + quad * 4;
        const int col = n0 - 1024 + wc * 64 + j * 16 + lcol;  // 0..511
#pragma unroll
        for (int r = 0; r < 4; ++r)
          z[(size_t)(row + r) * 512 + col] = acc[i][j][r];
      }
  }
}

// ---------------------------------------------------------------------------
// K2: scores tile (128x128) of q @ k^T with fused per-row max epilogue.
// qk: [8192][1024] bf16, A = cols 0..511 (q), B = cols 512..1023 (k).
// wsmx[coltile][m] : per-query max over this 128-col tile (coltile in [0,64))
__global__ __launch_bounds__(256) void gemm_scores(const short* __restrict__ qk,
                                                   float* __restrict__ wsmx) {
  __shared__ short lds_a[128 * 32];
  __shared__ short lds_b[128 * 32];
  __shared__ float partial[128][2];
  const int tid = threadIdx.x;
  const int w = tid >> 6, lane = tid & 63;
  const int wr = w >> 1, wc = w & 1;
  const int quad = lane >> 4, lcol = lane & 15;
  const int srow = w * 16 + (lane >> 2);
  const int skoff = (lane & 3) * 8;
  const int m0 = blockIdx.x * 128;
  const int n0 = blockIdx.y * 128;

  f32x4 acc[4][4];
#pragma unroll
  for (int i = 0; i < 4; ++i)
#pragma unroll
    for (int j = 0; j < 4; ++j)
#pragma unroll
      for (int r = 0; r < 4; ++r) acc[i][j][r] = 0.f;

  const short* Abase = qk + (size_t)(m0 + srow) * 1024 + skoff;
  const short* Bbase = qk + (size_t)(n0 + srow) * 1024 + 512 + skoff;
  short* la = lds_a + (w * 16) * 32;
  short* lb = lds_b + (w * 16) * 32;

  for (int kt = 0; kt < 16; ++kt) {
    const int kb = kt * 32;
    __syncthreads();
    gload_lds16(Abase + kb, la);
    gload_lds16(Abase + kb + (size_t)64 * 1024, la + 64 * 32);
    gload_lds16(Bbase + kb, lb);
    gload_lds16(Bbase + kb + (size_t)64 * 1024, lb + 64 * 32);
    __syncthreads();
    bf16x8 af[4], bf[4];
#pragma unroll
    for (int i = 0; i < 4; ++i)
      af[i] = *(const bf16x8*)&lds_a[(wr * 64 + i * 16 + lcol) * 32 + quad * 8];
#pragma unroll
    for (int j = 0; j < 4; ++j)
      bf[j] = *(const bf16x8*)&lds_b[(wc * 64 + j * 16 + lcol) * 32 + quad * 8];
#pragma unroll
    for (int i = 0; i < 4; ++i)
#pragma unroll
      for (int j = 0; j < 4; ++j)
        acc[i][j] = __builtin_amdgcn_mfma_f32_16x16x32_bf16(af[i], bf[j], acc[i][j], 0, 0, 0);
  }

  // per-row max over this wave's 64 cols; rows: wr*64 + i*16 + quad*4 + r
#pragma unroll
  for (int i = 0; i < 4; ++i) {
#pragma unroll
    for (int r = 0; r < 4; ++r) {
      float v = fmaxf(fmaxf(acc[i][0][r], acc[i][1][r]),
                      fmaxf(acc[i][2][r], acc[i][3][r]));
#pragma unroll
      for (int off = 1; off < 16; off <<= 1) v = fmaxf(v, __shfl_xor(v, off));
      if (lcol == 0) partial[wr * 64 + i * 16 + quad * 4 + r][wc] = v;
    }
  }
  __syncthreads();
  if (tid < 128)
    wsmx[(size_t)blockIdx.y * 8192 + m0 + tid] = fmaxf(partial[tid][0], partial[tid][1]);
}

// ---------------------------------------------------------------------------
// K3: per-query logit = mean over images of per-image max, * scale; softmax per image.
// grid 8 (one block per image), block 1024 (one thread per pixel)
__global__ __launch_bounds__(1024) void softmax_xw(const float* __restrict__ wsmx,
                                                   float* __restrict__ xw) {
  const int b = blockIdx.x, p = threadIdx.x;
  const int m = b * 1024 + p;
  float s = 0.f;
#pragma unroll
  for (int img = 0; img < 8; ++img) {
    float mx = -1e30f;
#pragma unroll
    for (int t = 0; t < 8; ++t) mx = fmaxf(mx, wsmx[(size_t)(img * 8 + t) * 8192 + m]);
    s += mx;
  }
  const float logit = s * 0.005524271728019903f;  // (1/8) * (1/sqrt(512))
  __shared__ float red[16];
  float v = logit;
#pragma unroll
  for (int off = 32; off >= 1; off >>= 1) v = fmaxf(v, __shfl_xor(v, off));
  if ((p & 63) == 0) red[p >> 6] = v;
  __syncthreads();
  float bmax = red[0];
#pragma unroll
  for (int t = 1; t < 16; ++t) bmax = fmaxf(bmax, red[t]);
  const float e = expf(logit - bmax);
  float sv = e;
#pragma unroll
  for (int off = 32; off >= 1; off >>= 1) sv += __shfl_xor(sv, off);
  __syncthreads();
  if ((p & 63) == 0) red[p >> 6] = sv;
  __syncthreads();
  float bsum = 0.f;
#pragma unroll
  for (int t = 0; t < 16; ++t) bsum += red[t];
  xw[m] = e / bsum;
}

// ---------------------------------------------------------------------------
// K4: out[b][co][p] = z[b*1024+p][co] * xw[b*1024+p] + b6[co]  (LDS transpose)
// grid (16 p-tiles, 8 c-tiles, 8 b), block 256
__global__ __launch_bounds__(256) void epilogue_out(const float* __restrict__ z,
                                                    const float* __restrict__ xw,
                                                    const float* __restrict__ b6,
                                                    float* __restrict__ out) {
  const int p0 = blockIdx.x * 64, c0 = blockIdx.y * 64, b = blockIdx.z;
  __shared__ float t[64][65];  // t[co][p]
  const int u = threadIdx.x;
  {
    const int c4 = u & 15, pr = u >> 4;
    for (int pp = 0; pp < 4; ++pp) {
      const int p = pp * 16 + pr;
      const float4 v = *(const float4*)&z[((size_t)(b * 1024 + p0 + p)) * 512 + c0 + c4 * 4];
      t[c4 * 4 + 0][p] = v.x;
      t[c4 * 4 + 1][p] = v.y;
      t[c4 * 4 + 2][p] = v.z;
      t[c4 * 4 + 3][p] = v.w;
    }
  }
  __syncthreads();
  {
    const int p4 = u & 15, cr = u >> 4;
    const float4 wv = *(const float4*)&xw[b * 1024 + p0 + p4 * 4];
    for (int cc = 0; cc < 4; ++cc) {
      const int co = cc * 16 + cr;
      const float bias = b6[c0 + co];
      float4 o;
      o.x = t[co][p4 * 4 + 0] * wv.x + bias;
      o.y = t[co][p4 * 4 + 1] * wv.y + bias;
      o.z = t[co][p4 * 4 + 2] * wv.z + bias;
      o.w = t[co][p4 * 4 + 3] * wv.w + bias;
      *(float4*)&out[((size_t)(b * 512 + c0 + co)) * 1024 + p0 + p4 * 4] = o;
    }
  }
}

// ---------------------------------------------------------------------------
extern "C" void kernel_launch(void* const* d_in, const int* in_sizes, int n_in,
                              void* d_out, int out_size, void* d_ws, size_t ws_size,
                              hipStream_t stream) {
  const float* x  = (const float*)d_in[0];
  const float* Wq = (const float*)d_in[1];
  const float* bq = (const float*)d_in[2];
  const float* Wk = (const float*)d_in[3];
  const float* bk = (const float*)d_in[4];
  const float* W6 = (const float*)d_in[5];
  const float* b6 = (const float*)d_in[6];
  float* out = (float*)d_out;

  char* ws = (char*)d_ws;
  short* xt   = (short*)(ws + 0);          //  8 MB  bf16 [8192][512]
  short* wcat = (short*)(ws + 8388608);    //  1.5MB bf16 [1536][512]
  short* qk   = (short*)(ws + 10485760);   // 16 MB  bf16 [8192][1024] (q|k)
  float* z    = (float*)(ws + 29360128);   // 16 MB  fp32 [8192][512]
  float* wsmx = (float*)(ws + 46137344);   //  2 MB  fp32 [64][8192]
  float* xw   = (float*)(ws + 48234496);   // 32 KB  fp32 [8192]

  transpose_x<<<dim3(16, 8, 8), 256, 0, stream>>>(x, xt);
  pack_w<<<768, 256, 0, stream>>>(Wq, Wk, W6, wcat);
  gemm_qkz<<<dim3(64, 12), 256, 0, stream>>>(xt, wcat, bq, bk, qk, z);
  gemm_scores<<<dim3(64, 64), 256, 0, stream>>>(qk, wsmx);
  softmax_xw<<<8, 1024, 0, stream>>>(wsmx, xw);
  epilogue_out<<<dim3(16, 8, 8), 256, 0, stream>>>(z, xw, b6, out);
}

// Round 2
// 195.002 us; speedup vs baseline: 1.0817x; 1.0817x over previous
//
#include <hip/hip_runtime.h>

// B=8, C=512, H=W=32, HW=1024, M=8192. scale = 1/sqrt(512).
// Pipeline: prep (x transpose->bf16, W pack->bf16) ; gemm_qk (bf16 MFMA -> fp8 q|k)
//           gemm_scores (fp8 MFMA, fused per-tile row-max) ; softmax ; gemm_out
//           (bf16 MFMA z = x@W6^T with gating*xw + bias fused, transposed store)

typedef __attribute__((ext_vector_type(8))) short bf16x8;
typedef __attribute__((ext_vector_type(4))) float f32x4;
typedef __attribute__((ext_vector_type(2))) long long i64x2;

__device__ __forceinline__ unsigned short f2bf(float f) {
  unsigned u = __builtin_bit_cast(unsigned, f);
  u += 0x7FFFu + ((u >> 16) & 1u);
  return (unsigned short)(u >> 16);
}

// float -> OCP e4m3fn, RNE, saturate to 448.
__device__ __forceinline__ unsigned char f2e4m3(float x) {
  unsigned u = __builtin_bit_cast(unsigned, x);
  unsigned char s = (unsigned char)((u >> 24) & 0x80u);
  unsigned a = u & 0x7FFFFFFFu;
  if (a >= 0x43E00000u) return s | 0x7Eu;      // clamp to 448
  if (a < 0x3C800000u) {                        // below 2^-6: subnormal (quantum 2^-9)
    float q = __builtin_bit_cast(float, a) * 512.f;
    int m = (int)(q + 0.5f);
    return s | (unsigned char)m;                // m==8 -> 0x08 == 2^-6 normal, correct
  }
  unsigned r = a + 0x7FFFFu + ((a >> 20) & 1u); // RNE at mantissa bit 20
  int e = (int)((r >> 23) & 0xFF) - 127;
  if (e > 8) return s | 0x7Eu;
  unsigned m3 = (r >> 20) & 0x7u;
  return s | (unsigned char)(((e + 7) << 3) | m3);
}

__device__ __forceinline__ void gload_lds16(const void* g, void* l) {
  __builtin_amdgcn_global_load_lds(
      (const __attribute__((address_space(1))) unsigned int*)g,
      (__attribute__((address_space(3))) unsigned int*)l, 16, 0, 0);
}

// ---------------------------------------------------------------------------
// prep: blocks [0,1024): transpose x [b][c][p] -> xt [b*1024+p][c] bf16
//       blocks [1024,1792): pack Wq|Wk|W6 -> wcat bf16 [1536][512]
__global__ __launch_bounds__(256) void prep(const float* __restrict__ x,
                                            const float* __restrict__ Wq,
                                            const float* __restrict__ Wk,
                                            const float* __restrict__ W6,
                                            short* __restrict__ xt,
                                            short* __restrict__ wcat) {
  const int bid = blockIdx.x, u = threadIdx.x;
  if (bid < 1024) {
    const int p0 = (bid & 15) * 64, c0 = ((bid >> 4) & 7) * 64, b = bid >> 7;
    __shared__ float t[64][65];
    {
      const int p4 = u & 15, cr = u >> 4;
      for (int cc = 0; cc < 4; ++cc) {
        const int c = cc * 16 + cr;
        const float4 v = *(const float4*)&x[((size_t)(b * 512 + c0 + c)) * 1024 + p0 + p4 * 4];
        t[p4 * 4 + 0][c] = v.x; t[p4 * 4 + 1][c] = v.y;
        t[p4 * 4 + 2][c] = v.z; t[p4 * 4 + 3][c] = v.w;
      }
    }
    __syncthreads();
    {
      const int c4 = u & 15, pr = u >> 4;
      for (int pp = 0; pp < 4; ++pp) {
        const int p = pp * 16 + pr;
        ushort4 o;
        o.x = f2bf(t[p][c4 * 4 + 0]); o.y = f2bf(t[p][c4 * 4 + 1]);
        o.z = f2bf(t[p][c4 * 4 + 2]); o.w = f2bf(t[p][c4 * 4 + 3]);
        *(ushort4*)&xt[((size_t)(b * 1024 + p0 + p)) * 512 + c0 + c4 * 4] = o;
      }
    }
  } else {
    const int i = (bid - 1024) * 256 + u;
    const int idx = i * 4;
    const float* src = (idx < 262144) ? Wq : (idx < 524288) ? Wk : W6;
    const float4 v = *(const float4*)&src[idx & 262143];
    ushort4 o;
    o.x = f2bf(v.x); o.y = f2bf(v.y); o.z = f2bf(v.z); o.w = f2bf(v.w);
    *(ushort4*)&wcat[idx] = o;
  }
}

// ---------------------------------------------------------------------------
// gemm_qk: [8192][1024] = xt @ wcat[0:1024]^T + bias -> fp8 qk8
// 128x128 tile, BK=32 (bf16), frag-ordered LDS: group g (16 rows) block = 1KB,
// layout addr = g*1024 + kq*256 + r*16 + byte  (kq = 16B k-chunk)
__global__ __launch_bounds__(256) void gemm_qk(const short* __restrict__ xt,
                                               const short* __restrict__ wcat,
                                               const float* __restrict__ bq,
                                               const float* __restrict__ bk,
                                               unsigned char* __restrict__ qk8) {
  __shared__ short lds_a[128 * 32];
  __shared__ short lds_b[128 * 32];
  const int tid = threadIdx.x, w = tid >> 6, lane = tid & 63;
  const int wr = w >> 1, wc = w & 1;
  const int quad = lane >> 4, lcol = lane & 15;
  const int skq = lane >> 4, srow = lane & 15;
  const int m0 = blockIdx.x * 128, n0 = blockIdx.y * 128;

  f32x4 acc[4][4];
#pragma unroll
  for (int i = 0; i < 4; ++i)
#pragma unroll
    for (int j = 0; j < 4; ++j)
#pragma unroll
      for (int r = 0; r < 4; ++r) acc[i][j][r] = 0.f;

  const short* Abase = xt + (size_t)(m0 + srow) * 512 + skq * 8;
  const short* Bbase = wcat + (size_t)(n0 + srow) * 512 + skq * 8;

  for (int kt = 0; kt < 16; ++kt) {
    const int kb = kt * 32;
    __syncthreads();
    gload_lds16(Abase + (size_t)(w * 16) * 512 + kb,       lds_a + w * 512);
    gload_lds16(Abase + (size_t)((4 + w) * 16) * 512 + kb, lds_a + (4 + w) * 512);
    gload_lds16(Bbase + (size_t)(w * 16) * 512 + kb,       lds_b + w * 512);
    gload_lds16(Bbase + (size_t)((4 + w) * 16) * 512 + kb, lds_b + (4 + w) * 512);
    __syncthreads();
    bf16x8 af[4], bf[4];
#pragma unroll
    for (int i = 0; i < 4; ++i) af[i] = *(const bf16x8*)&lds_a[(wr * 4 + i) * 512 + lane * 8];
#pragma unroll
    for (int j = 0; j < 4; ++j) bf[j] = *(const bf16x8*)&lds_b[(wc * 4 + j) * 512 + lane * 8];
#pragma unroll
    for (int i = 0; i < 4; ++i)
#pragma unroll
      for (int j = 0; j < 4; ++j)
        acc[i][j] = __builtin_amdgcn_mfma_f32_16x16x32_bf16(af[i], bf[j], acc[i][j], 0, 0, 0);
  }

  const float* bias = (blockIdx.y >= 4) ? bk : bq;
#pragma unroll
  for (int i = 0; i < 4; ++i)
#pragma unroll
    for (int j = 0; j < 4; ++j) {
      const int row = m0 + wr * 64 + i * 16 + quad * 4;
      const int col = n0 + wc * 64 + j * 16 + lcol;
      const float bv = bias[col & 511];
#pragma unroll
      for (int r = 0; r < 4; ++r)
        qk8[(size_t)(row + r) * 1024 + col] = f2e4m3(acc[i][j][r] + bv);
    }
}

// ---------------------------------------------------------------------------
// gemm_scores: q @ k^T (fp8 MFMA), fused per-row max over each 128-col tile.
// BK=64 bytes; frag-ordered LDS; each lane's 16B = k-bytes [quad*16,+16):
// low 8B -> mfma step0, high 8B -> step1 (same permutation for A and B).
__global__ __launch_bounds__(256) void gemm_scores(const unsigned char* __restrict__ qk8,
                                                   float* __restrict__ wsmx) {
  __shared__ unsigned char lds_a[8192];
  __shared__ unsigned char lds_b[8192];
  __shared__ float partial[128][2];
  const int tid = threadIdx.x, w = tid >> 6, lane = tid & 63;
  const int wr = w >> 1, wc = w & 1;
  const int quad = lane >> 4, lcol = lane & 15;
  const int skq = lane >> 4, srow = lane & 15;
  const int m0 = blockIdx.x * 128, n0 = blockIdx.y * 128;

  f32x4 acc[4][4];
#pragma unroll
  for (int i = 0; i < 4; ++i)
#pragma unroll
    for (int j = 0; j < 4; ++j)
#pragma unroll
      for (int r = 0; r < 4; ++r) acc[i][j][r] = 0.f;

  const unsigned char* Abase = qk8 + (size_t)(m0 + srow) * 1024 + skq * 16;
  const unsigned char* Bbase = qk8 + (size_t)(n0 + srow) * 1024 + 512 + skq * 16;

  for (int kt = 0; kt < 8; ++kt) {
    const int kb = kt * 64;
    __syncthreads();
    gload_lds16(Abase + (size_t)(w * 16) * 1024 + kb,       lds_a + w * 1024);
    gload_lds16(Abase + (size_t)((4 + w) * 16) * 1024 + kb, lds_a + (4 + w) * 1024);
    gload_lds16(Bbase + (size_t)(w * 16) * 1024 + kb,       lds_b + w * 1024);
    gload_lds16(Bbase + (size_t)((4 + w) * 16) * 1024 + kb, lds_b + (4 + w) * 1024);
    __syncthreads();
    i64x2 af[4], bf[4];
#pragma unroll
    for (int i = 0; i < 4; ++i) af[i] = *(const i64x2*)&lds_a[(wr * 4 + i) * 1024 + lane * 16];
#pragma unroll
    for (int j = 0; j < 4; ++j) bf[j] = *(const i64x2*)&lds_b[(wc * 4 + j) * 1024 + lane * 16];
#pragma unroll
    for (int i = 0; i < 4; ++i)
#pragma unroll
      for (int j = 0; j < 4; ++j) {
        acc[i][j] = __builtin_amdgcn_mfma_f32_16x16x32_fp8_fp8(af[i].x, bf[j].x, acc[i][j], 0, 0, 0);
        acc[i][j] = __builtin_amdgcn_mfma_f32_16x16x32_fp8_fp8(af[i].y, bf[j].y, acc[i][j], 0, 0, 0);
      }
  }

#pragma unroll
  for (int i = 0; i < 4; ++i) {
#pragma unroll
    for (int r = 0; r < 4; ++r) {
      float v = fmaxf(fmaxf(acc[i][0][r], acc[i][1][r]),
                      fmaxf(acc[i][2][r], acc[i][3][r]));
#pragma unroll
      for (int off = 1; off < 16; off <<= 1) v = fmaxf(v, __shfl_xor(v, off));
      if (lcol == 0) partial[wr * 64 + i * 16 + quad * 4 + r][wc] = v;
    }
  }
  __syncthreads();
  if (tid < 128)
    wsmx[(size_t)blockIdx.y * 8192 + m0 + tid] = fmaxf(partial[tid][0], partial[tid][1]);
}

// ---------------------------------------------------------------------------
// softmax_xw: logit[m] = scale * mean_img( max over img's 8 col-tiles ); softmax per image
__global__ __launch_bounds__(1024) void softmax_xw(const float* __restrict__ wsmx,
                                                   float* __restrict__ xw) {
  const int b = blockIdx.x, p = threadIdx.x;
  const int m = b * 1024 + p;
  float s = 0.f;
#pragma unroll
  for (int img = 0; img < 8; ++img) {
    float mx = -1e30f;
#pragma unroll
    for (int t = 0; t < 8; ++t) mx = fmaxf(mx, wsmx[(size_t)(img * 8 + t) * 8192 + m]);
    s += mx;
  }
  const float logit = s * 0.005524271728019903f;  // (1/8) * (1/sqrt(512))
  __shared__ float red[16];
  float v = logit;
#pragma unroll
  for (int off = 32; off >= 1; off >>= 1) v = fmaxf(v, __shfl_xor(v, off));
  if ((p & 63) == 0) red[p >> 6] = v;
  __syncthreads();
  float bmax = red[0];
#pragma unroll
  for (int t = 1; t < 16; ++t) bmax = fmaxf(bmax, red[t]);
  const float e = expf(logit - bmax);
  float sv = e;
#pragma unroll
  for (int off = 32; off >= 1; off >>= 1) sv += __shfl_xor(sv, off);
  __syncthreads();
  if ((p & 63) == 0) red[p >> 6] = sv;
  __syncthreads();
  float bsum = 0.f;
#pragma unroll
  for (int t = 0; t < 16; ++t) bsum += red[t];
  xw[m] = e / bsum;
}

// ---------------------------------------------------------------------------
// gemm_out: out[b][co][p] = (xt @ W6^T)[m][co] * xw[m] + b6[co], m = b*1024+p.
// Same bf16 frag-ordered structure; acc quads are p-contiguous -> float4 stores.
__global__ __launch_bounds__(256) void gemm_out(const short* __restrict__ xt,
                                                const short* __restrict__ wcat,
                                                const float* __restrict__ xw,
                                                const float* __restrict__ b6,
                                                float* __restrict__ out) {
  __shared__ short lds_a[128 * 32];
  __shared__ short lds_b[128 * 32];
  const int tid = threadIdx.x, w = tid >> 6, lane = tid & 63;
  const int wr = w >> 1, wc = w & 1;
  const int quad = lane >> 4, lcol = lane & 15;
  const int skq = lane >> 4, srow = lane & 15;
  const int m0 = blockIdx.x * 128, n0 = blockIdx.y * 128;

  f32x4 acc[4][4];
#pragma unroll
  for (int i = 0; i < 4; ++i)
#pragma unroll
    for (int j = 0; j < 4; ++j)
#pragma unroll
      for (int r = 0; r < 4; ++r) acc[i][j][r] = 0.f;

  const short* Abase = xt + (size_t)(m0 + srow) * 512 + skq * 8;
  const short* Bbase = wcat + (size_t)(1024 + n0 + srow) * 512 + skq * 8;

  for (int kt = 0; kt < 16; ++kt) {
    const int kb = kt * 32;
    __syncthreads();
    gload_lds16(Abase + (size_t)(w * 16) * 512 + kb,       lds_a + w * 512);
    gload_lds16(Abase + (size_t)((4 + w) * 16) * 512 + kb, lds_a + (4 + w) * 512);
    gload_lds16(Bbase + (size_t)(w * 16) * 512 + kb,       lds_b + w * 512);
    gload_lds16(Bbase + (size_t)((4 + w) * 16) * 512 + kb, lds_b + (4 + w) * 512);
    __syncthreads();
    bf16x8 af[4], bf[4];
#pragma unroll
    for (int i = 0; i < 4; ++i) af[i] = *(const bf16x8*)&lds_a[(wr * 4 + i) * 512 + lane * 8];
#pragma unroll
    for (int j = 0; j < 4; ++j) bf[j] = *(const bf16x8*)&lds_b[(wc * 4 + j) * 512 + lane * 8];
#pragma unroll
    for (int i = 0; i < 4; ++i)
#pragma unroll
      for (int j = 0; j < 4; ++j)
        acc[i][j] = __builtin_amdgcn_mfma_f32_16x16x32_bf16(af[i], bf[j], acc[i][j], 0, 0, 0);
  }

#pragma unroll
  for (int i = 0; i < 4; ++i) {
    const int mbase = m0 + wr * 64 + i * 16 + quad * 4;
    const int b = mbase >> 10, p = mbase & 1023;
    const float4 wv = *(const float4*)&xw[mbase];
#pragma unroll
    for (int j = 0; j < 4; ++j) {
      const int col = n0 + wc * 64 + j * 16 + lcol;
      const float bias = b6[col];
      float4 o;
      o.x = acc[i][j][0] * wv.x + bias;
      o.y = acc[i][j][1] * wv.y + bias;
      o.z = acc[i][j][2] * wv.z + bias;
      o.w = acc[i][j][3] * wv.w + bias;
      *(float4*)&out[((size_t)(b * 512 + col)) * 1024 + p] = o;
    }
  }
}

// ---------------------------------------------------------------------------
extern "C" void kernel_launch(void* const* d_in, const int* in_sizes, int n_in,
                              void* d_out, int out_size, void* d_ws, size_t ws_size,
                              hipStream_t stream) {
  const float* x  = (const float*)d_in[0];
  const float* Wq = (const float*)d_in[1];
  const float* bq = (const float*)d_in[2];
  const float* Wk = (const float*)d_in[3];
  const float* bk = (const float*)d_in[4];
  const float* W6 = (const float*)d_in[5];
  const float* b6 = (const float*)d_in[6];
  float* out = (float*)d_out;

  char* ws = (char*)d_ws;
  short* xt          = (short*)(ws + 0);          //  8 MB  bf16 [8192][512]
  short* wcat        = (short*)(ws + 8388608);    //  1.5MB bf16 [1536][512]
  unsigned char* qk8 = (unsigned char*)(ws + 10485760);  // 8 MB fp8 [8192][1024]
  float* wsmx        = (float*)(ws + 18874368);   //  2 MB  fp32 [64][8192]
  float* xw          = (float*)(ws + 20971520);   // 32 KB  fp32 [8192]

  prep<<<1792, 256, 0, stream>>>(x, Wq, Wk, W6, xt, wcat);
  gemm_qk<<<dim3(64, 8), 256, 0, stream>>>(xt, wcat, bq, bk, qk8);
  gemm_scores<<<dim3(64, 64), 256, 0, stream>>>(qk8, wsmx);
  softmax_xw<<<8, 1024, 0, stream>>>(wsmx, xw);
  gemm_out<<<dim3(64, 4), 256, 0, stream>>>(xt, wcat, xw, b6, out);
}